// Round 5
// baseline (732.098 us; speedup 1.0000x reference)
//
#include <hip/hip_runtime.h>
#include <stdint.h>

#define TT 300

// ws layout (floats)
#define XW0_OFF 0
#define XW0_SZ  (TT*4*1024)
#define HQ0_OFF (XW0_OFF + XW0_SZ)
#define HQ_SZ   (TT*1024*2)          // {h,tag} pairs, 2 floats each
#define HQ1_OFF (HQ0_OFF + HQ_SZ)
#define NPAIRS_TOT (TT*1024*2)       // pairs across hq0+hq1 (contiguous)

typedef short s16x8 __attribute__((ext_vector_type(8)));
typedef float f32x4 __attribute__((ext_vector_type(4)));

__device__ __forceinline__ float sigf(float x){ return 1.0f/(1.0f+__expf(-x)); }
__device__ __forceinline__ float tahf(float x){ return 1.0f-2.0f/(__expf(2.0f*x)+1.0f); }
__device__ __forceinline__ short f2bf(float f){ __bf16 h=(__bf16)f; return __builtin_bit_cast(short,h); }

// LLC-coherent loads (bypass L1/L2, no invalidates); one vmcnt per group
__device__ __forceinline__ void llc_load32(const float* p, uint4& a, uint4& b) {
  asm volatile("global_load_dwordx4 %0, %2, off sc0 sc1\n\t"
               "global_load_dwordx4 %1, %2, off offset:16 sc0 sc1\n\t"
               "s_waitcnt vmcnt(0)"
               : "=&v"(a), "=&v"(b) : "v"(p) : "memory");
}
__device__ __forceinline__ void llc_load64(const float* p0, const float* p1,
                                           uint4& a, uint4& b, uint4& c, uint4& d) {
  asm volatile("global_load_dwordx4 %0, %4, off sc0 sc1\n\t"
               "global_load_dwordx4 %1, %4, off offset:16 sc0 sc1\n\t"
               "global_load_dwordx4 %2, %5, off sc0 sc1\n\t"
               "global_load_dwordx4 %3, %5, off offset:16 sc0 sc1\n\t"
               "s_waitcnt vmcnt(0)"
               : "=&v"(a), "=&v"(b), "=&v"(c), "=&v"(d) : "v"(p0), "v"(p1) : "memory");
}
// packed {h, tag} 8B store -> data+flag visible atomically (LLC)
__device__ __forceinline__ void llc_store_pair(float* p, float h, unsigned tag) {
  union { struct { float h; unsigned t; } s; unsigned long long u; } pk;
  pk.s.h = h; pk.s.t = tag;
  __hip_atomic_store((unsigned long long*)p, pk.u,
                     __ATOMIC_RELAXED, __HIP_MEMORY_SCOPE_AGENT);
}

// ------------- embedding gather + layer0 input projection + hq tag zero ----
__global__ void emb_proj_k(const float* __restrict__ enc, const int* __restrict__ inp,
                           const float* __restrict__ Wih0, const float* __restrict__ bih0,
                           const float* __restrict__ bhh0, float* __restrict__ xw0,
                           float* __restrict__ hqz)
{
  __shared__ float xl[100];
  const int t = blockIdx.x;
  const int tid = threadIdx.x;
  // zero all {h,tag} pairs (agent-scope so scan's sc0sc1 polls see them)
  for (size_t i = (size_t)t*256 + tid; i < (size_t)NPAIRS_TOT; i += (size_t)TT*256)
    llc_store_pair(hqz + i*2, 0.f, 0u);
  if (tid < 100) {
    int q = t*100 + tid;
    int s = q / 1200;
    int rm = q - s*1200;
    int bb = rm / 300;
    int e  = rm - bb*300;
    int tok = inp[bb*25 + s];
    xl[tid] = enc[(long)tok*300 + e];
  }
  __syncthreads();
  for (int rr = 0; rr < 4; ++rr) {
    int row = rr*256 + tid;
    const float* wr = Wih0 + row*25;
    float bias = bih0[row] + bhh0[row];
    float a0 = bias, a1 = bias, a2 = bias, a3 = bias;
#pragma unroll
    for (int i = 0; i < 25; ++i) {
      float w = wr[i];
      a0 += w * xl[i];
      a1 += w * xl[25+i];
      a2 += w * xl[50+i];
      a3 += w * xl[75+i];
    }
    xw0[(t*4+0)*1024 + row] = a0;
    xw0[(t*4+1)*1024 + row] = a1;
    xw0[(t*4+2)*1024 + row] = a2;
    xw0[(t*4+3)*1024 + row] = a3;
  }
}

// ---------------- persistent 2-layer LSTM scan, MFMA, 12 WGs ---------------
// WG 0..3  : layer0, units [wid*64, +64), K=256 (h0 only; xw0 precomputed)
// WG 4..11 : layer1, units [(wid-4)*32, +32), K=512 = concat(y0[t], h1[t-1])
// Weights resident in VGPRs as bf16 hi+lo fragment pairs; f32 MFMA accum.
// Sync: fused {h,tag} pairs via LLC; L1 lags L0 (streaming y0), the only
// per-step serial deps are each layer's own h broadcast.
__global__ __launch_bounds__(256, 1) void scan_k(
    const float* __restrict__ Whh0, const float* __restrict__ Wih1,
    const float* __restrict__ Whh1, const float* __restrict__ bih1,
    const float* __restrict__ bhh1, const float* __restrict__ h0in,
    const float* __restrict__ c0in, const float* __restrict__ xw0,
    float* __restrict__ hq0, float* __restrict__ hq1,
    float* __restrict__ dout)
{
  const int wid  = blockIdx.x;
  const int tid  = threadIdx.x;
  const int lane = tid & 63;
  const int wv   = tid >> 6;          // wave 0..3
  const int ln15 = lane & 15;         // A-row within tile / B-col (batch)
  const int kg   = lane >> 4;         // k-group 0..3
  const int layer = (wid < 4) ? 0 : 1;

  // B-operand staging: hb[b(16)][k + pad]; stride 520 ushort = 1040B
  //   -> 16B-aligned rows, dword-bank stagger 4 per b (conflict-free b128)
  __shared__ ushort hb[16][520];
  __shared__ float  gl[1280];         // gate pre-activations [row][b] pad 5

  // ---- weight fragments: W = Whi + Wlo (bf16 pair), A-slot (kg, j) = k
  s16x8 whi[32], wlo[32];
  if (layer == 0) {
#pragma unroll
    for (int q = 0; q < 4; ++q) {
      int r = (wv*4 + q)*16 + ln15;   // local row
      int g = r >> 6, ul = r & 63;
      const float* wr = Whh0 + (size_t)(g*256 + wid*64 + ul)*256;
#pragma unroll
      for (int kt = 0; kt < 8; ++kt) {
        s16x8 hi, lo;
#pragma unroll
        for (int j = 0; j < 8; ++j) {
          float w = wr[kt*32 + kg*8 + j];
          __bf16 hh = (__bf16)w; float hf = (float)hh;
          hi[j] = __builtin_bit_cast(short, hh);
          lo[j] = __builtin_bit_cast(short, (__bf16)(w - hf));
        }
        whi[q*8 + kt] = hi; wlo[q*8 + kt] = lo;
      }
    }
  } else {
#pragma unroll
    for (int q = 0; q < 2; ++q) {
      int r = (wv*2 + q)*16 + ln15;
      int g = r >> 5, ul = r & 31;
      size_t grow = (size_t)(g*256 + (wid-4)*32 + ul);
      const float* wi = Wih1 + grow*256;
      const float* wh = Whh1 + grow*256;
#pragma unroll
      for (int kt = 0; kt < 16; ++kt) {
        const float* wr = (kt < 8) ? (wi + kt*32) : (wh + (kt-8)*32);
        s16x8 hi, lo;
#pragma unroll
        for (int j = 0; j < 8; ++j) {
          float w = wr[kg*8 + j];
          __bf16 hh = (__bf16)w; float hf = (float)hh;
          hi[j] = __builtin_bit_cast(short, hh);
          lo[j] = __builtin_bit_cast(short, (__bf16)(w - hf));
        }
        whi[q*16 + kt] = hi; wlo[q*16 + kt] = lo;
      }
    }
  }

  // ---- gate-math thread state: (u, b) owns cell c[u][b] in a register
  const int u = tid >> 2, b = tid & 3;
  const bool gthr = (layer == 0) ? true : (tid < 128);
  int gu = 0; float cpr = 0.f, bs0=0.f, bs1=0.f, bs2=0.f, bs3=0.f;
  if (gthr) {
    gu = (layer == 0) ? (wid*64 + u) : ((wid-4)*32 + u);
    cpr = c0in[layer*1024 + b*256 + gu];
    if (layer == 1) {
      bs0 = bih1[0*256+gu] + bhh1[0*256+gu];
      bs1 = bih1[1*256+gu] + bhh1[1*256+gu];
      bs2 = bih1[2*256+gu] + bhh1[2*256+gu];
      bs3 = bih1[3*256+gu] + bhh1[3*256+gu];
    }
  }

  // ---- zero B-operand batch cols 4..15 once (stay zero forever)
  for (int i = tid; i < 12*520; i += 256) hb[4 + i/520][i%520] = 0;

  const int UN = layer ? 32 : 64;     // local rows per gate

  for (int t = 0; t < TT; ++t) {
    // -- L0 gate-input prefetch (plain cached; drains with poll's vmcnt)
    float xwa=0.f, xwb=0.f, xwc=0.f, xwd=0.f;
    if (layer == 0) {
      const float* xp = xw0 + (size_t)(t*4 + b)*1024 + gu;
      xwa = xp[0]; xwb = xp[256]; xwc = xp[512]; xwd = xp[768];
    }

    // -- poll fused {h,tag} pairs, stage to hb as bf16
    if (layer == 0) {
      if (t == 0) {
        hb[0][tid] = f2bf(h0in[0*256 + tid]);
        hb[1][tid] = f2bf(h0in[1*256 + tid]);
        hb[2][tid] = f2bf(h0in[2*256 + tid]);
        hb[3][tid] = f2bf(h0in[3*256 + tid]);
      } else {
        const float* pp = hq0 + ((size_t)(t-1)*1024 + tid*4)*2;
        const unsigned tg = (unsigned)t;
        unsigned gd = 0; uint4 q1, q2;
        do { llc_load32(pp, q1, q2); }
        while ((q1.y != tg || q1.w != tg || q2.y != tg || q2.w != tg) &&
               ++gd < (1u<<20));
        hb[0][tid] = f2bf(__uint_as_float(q1.x));
        hb[1][tid] = f2bf(__uint_as_float(q1.z));
        hb[2][tid] = f2bf(__uint_as_float(q2.x));
        hb[3][tid] = f2bf(__uint_as_float(q2.z));
      }
    } else {
      const float* py = hq0 + ((size_t)t*1024 + tid*4)*2;   // y0[t]
      const unsigned tgy = (unsigned)(t+1);
      if (t == 0) {
        unsigned gd = 0; uint4 q1, q2;
        do { llc_load32(py, q1, q2); }
        while ((q1.y != tgy || q1.w != tgy || q2.y != tgy || q2.w != tgy) &&
               ++gd < (1u<<20));
        hb[0][tid] = f2bf(__uint_as_float(q1.x));
        hb[1][tid] = f2bf(__uint_as_float(q1.z));
        hb[2][tid] = f2bf(__uint_as_float(q2.x));
        hb[3][tid] = f2bf(__uint_as_float(q2.z));
        hb[0][256+tid] = f2bf(h0in[1024 + 0*256 + tid]);
        hb[1][256+tid] = f2bf(h0in[1024 + 1*256 + tid]);
        hb[2][256+tid] = f2bf(h0in[1024 + 2*256 + tid]);
        hb[3][256+tid] = f2bf(h0in[1024 + 3*256 + tid]);
      } else {
        const float* ph = hq1 + ((size_t)(t-1)*1024 + tid*4)*2;
        const unsigned tgh = (unsigned)t;
        unsigned gd = 0; uint4 q1, q2, q3, q4;
        do { llc_load64(py, ph, q1, q2, q3, q4); }
        while ((q1.y != tgy || q1.w != tgy || q2.y != tgy || q2.w != tgy ||
                q3.y != tgh || q3.w != tgh || q4.y != tgh || q4.w != tgh) &&
               ++gd < (1u<<20));
        hb[0][tid] = f2bf(__uint_as_float(q1.x));
        hb[1][tid] = f2bf(__uint_as_float(q1.z));
        hb[2][tid] = f2bf(__uint_as_float(q2.x));
        hb[3][tid] = f2bf(__uint_as_float(q2.z));
        hb[0][256+tid] = f2bf(__uint_as_float(q3.x));
        hb[1][256+tid] = f2bf(__uint_as_float(q3.z));
        hb[2][256+tid] = f2bf(__uint_as_float(q4.x));
        hb[3][256+tid] = f2bf(__uint_as_float(q4.z));
      }
    }
    __syncthreads();                  // B1: staging ready

    // -- MFMA: D[row][batch] over resident W pair fragments
    f32x4 acc[4];
#pragma unroll
    for (int q = 0; q < 4; ++q) acc[q] = (f32x4){0.f,0.f,0.f,0.f};
    if (layer == 0) {
#pragma unroll
      for (int kt = 0; kt < 8; ++kt) {
        s16x8 bfr = *(const s16x8*)&hb[ln15][kt*32 + kg*8];
#pragma unroll
        for (int q = 0; q < 4; ++q) {
          acc[q] = __builtin_amdgcn_mfma_f32_16x16x32_bf16(whi[q*8+kt], bfr, acc[q], 0,0,0);
          acc[q] = __builtin_amdgcn_mfma_f32_16x16x32_bf16(wlo[q*8+kt], bfr, acc[q], 0,0,0);
        }
      }
      if (ln15 < 4) {
#pragma unroll
        for (int q = 0; q < 4; ++q) {
          int rt = wv*4 + q;
#pragma unroll
          for (int i = 0; i < 4; ++i)
            gl[(rt*16 + kg*4 + i)*5 + ln15] = acc[q][i];
        }
      }
    } else {
#pragma unroll
      for (int kt = 0; kt < 16; ++kt) {
        s16x8 bfr = *(const s16x8*)&hb[ln15][kt*32 + kg*8];
#pragma unroll
        for (int q = 0; q < 2; ++q) {
          acc[q] = __builtin_amdgcn_mfma_f32_16x16x32_bf16(whi[q*16+kt], bfr, acc[q], 0,0,0);
          acc[q] = __builtin_amdgcn_mfma_f32_16x16x32_bf16(wlo[q*16+kt], bfr, acc[q], 0,0,0);
        }
      }
      if (ln15 < 4) {
#pragma unroll
        for (int q = 0; q < 2; ++q) {
          int rt = wv*2 + q;
#pragma unroll
          for (int i = 0; i < 4; ++i)
            gl[(rt*16 + kg*4 + i)*5 + ln15] = acc[q][i];
        }
      }
    }
    __syncthreads();                  // B2: gates ready

    // -- gate math: thread (u,b), cell state in register, publish {h,tag}
    if (gthr) {
      float gi = gl[(0*UN + u)*5 + b] + (layer ? bs0 : xwa);
      float gf = gl[(1*UN + u)*5 + b] + (layer ? bs1 : xwb);
      float gc = gl[(2*UN + u)*5 + b] + (layer ? bs2 : xwc);
      float go = gl[(3*UN + u)*5 + b] + (layer ? bs3 : xwd);
      float cn = sigf(gf)*cpr + sigf(gi)*tahf(gc);
      float hn = sigf(go)*tahf(cn);
      cpr = cn;
      float* hq = layer ? hq1 : hq0;
      llc_store_pair(hq + ((size_t)t*1024 + gu*4 + b)*2, hn, (unsigned)(t+1));
      if (t == TT-1) {
        dout[400000 + layer*1024 + b*256 + gu] = hn;
        dout[400000 + 2048 + layer*1024 + b*256 + gu] = cn;
      }
    }
    // no 3rd barrier: next-step hb/gl writes are ordered by B1/B2 of t+1
  }
}

// ---------------- fc + relu + vocab decode --------------------------------
__global__ void decode_k(const float* __restrict__ y1p, const float* __restrict__ fcW,
                         const float* __restrict__ fcb, const float* __restrict__ decW,
                         const float* __restrict__ decb, float* __restrict__ dout)
{
  __shared__ float y1[1024];   // [j][b]
  __shared__ float o10[40];    // [kk][b]
  const int tid = threadIdx.x;
#pragma unroll
  for (int b = 0; b < 4; ++b)
    y1[tid*4 + b] = y1p[(size_t)(tid*4 + b)*2];   // strip tags
  __syncthreads();
  if (tid < 40) {
    int kk = tid >> 2, b = tid & 3;
    float a = fcb[kk];
    for (int j = 0; j < 256; ++j) a += fcW[kk*256 + j] * y1[j*4 + b];
    o10[kk*4 + b] = fmaxf(a, 0.f);
  }
  __syncthreads();
  int v = blockIdx.x*256 + tid;
  if (v < 100000) {
    const float* dr = decW + (size_t)v*10;
    float bias = decb[v];
    float a0 = bias, a1 = bias, a2 = bias, a3 = bias;
#pragma unroll
    for (int kk = 0; kk < 10; ++kk) {
      float w = dr[kk];
      a0 += w * o10[kk*4+0];
      a1 += w * o10[kk*4+1];
      a2 += w * o10[kk*4+2];
      a3 += w * o10[kk*4+3];
    }
    float4 o; o.x = a0; o.y = a1; o.z = a2; o.w = a3;
    ((float4*)dout)[v] = o;   // decoded.T[v][0..3]
  }
}

extern "C" void kernel_launch(void* const* d_in, const int* in_sizes, int n_in,
                              void* d_out, int out_size, void* d_ws, size_t ws_size,
                              hipStream_t stream)
{
  const float* enc  = (const float*)d_in[0];
  const float* h0in = (const float*)d_in[1];
  const float* c0in = (const float*)d_in[2];
  const float* Wih0 = (const float*)d_in[3];
  const float* Whh0 = (const float*)d_in[4];
  const float* bih0 = (const float*)d_in[5];
  const float* bhh0 = (const float*)d_in[6];
  const float* Wih1 = (const float*)d_in[7];
  const float* Whh1 = (const float*)d_in[8];
  const float* bih1 = (const float*)d_in[9];
  const float* bhh1 = (const float*)d_in[10];
  const float* fcW  = (const float*)d_in[11];
  const float* fcb  = (const float*)d_in[12];
  const float* decW = (const float*)d_in[13];
  const float* decb = (const float*)d_in[14];
  const int*   inp  = (const int*)d_in[15];

  float* ws   = (float*)d_ws;
  float* xw0  = ws + XW0_OFF;
  float* hq0  = ws + HQ0_OFF;
  float* hq1  = ws + HQ1_OFF;
  float* dout = (float*)d_out;

  emb_proj_k<<<TT, 256, 0, stream>>>(enc, inp, Wih0, bih0, bhh0, xw0, hq0);
  scan_k<<<12, 256, 0, stream>>>(Whh0, Wih1, Whh1, bih1, bhh1,
                                 h0in, c0in, xw0, hq0, hq1, dout);
  decode_k<<<(100000 + 255)/256, 256, 0, stream>>>(hq1 + (size_t)(TT-1)*1024*2,
                                                   fcW, fcb, decW, decb, dout);
}

// Round 6
// 619.326 us; speedup vs baseline: 1.1821x; 1.1821x over previous
//
#include <hip/hip_runtime.h>
#include <stdint.h>

#define TT 300

// ws layout (floats)
#define XW0_OFF 0
#define XW0_SZ  (TT*4*1024)
#define HQ0_OFF (XW0_OFF + XW0_SZ)
#define HQ_SZ   (TT*1024*2)          // {h,tag} pairs, 2 floats each
#define HQ1_OFF (HQ0_OFF + HQ_SZ)
#define NPAIRS_TOT (TT*1024*2)       // pairs across hq0+hq1 (contiguous)

typedef _Float16 f16x8 __attribute__((ext_vector_type(8)));
typedef float    f32x4 __attribute__((ext_vector_type(4)));

__device__ __forceinline__ float sigf(float x){ return 1.0f/(1.0f+__expf(-x)); }
__device__ __forceinline__ float tahf(float x){ return 1.0f-2.0f/(__expf(2.0f*x)+1.0f); }

// LLC-coherent loads (bypass L1/L2, no invalidates); one vmcnt per group
__device__ __forceinline__ uint4 llc_load16(const float* p) {
  uint4 v;
  asm volatile("global_load_dwordx4 %0, %1, off sc0 sc1\n\t"
               "s_waitcnt vmcnt(0)"
               : "=v"(v) : "v"(p) : "memory");
  return v;
}
// two 16B loads from two different addresses, one vmcnt
__device__ __forceinline__ void llc_load16x2(const float* p0, const float* p1,
                                             uint4& a, uint4& b) {
  asm volatile("global_load_dwordx4 %0, %2, off sc0 sc1\n\t"
               "global_load_dwordx4 %1, %3, off sc0 sc1\n\t"
               "s_waitcnt vmcnt(0)"
               : "=&v"(a), "=&v"(b) : "v"(p0), "v"(p1) : "memory");
}
// packed {h, tag} 8B store -> data+flag visible atomically (LLC)
__device__ __forceinline__ void llc_store_pair(float* p, float h, unsigned tag) {
  union { struct { float h; unsigned t; } s; unsigned long long u; } pk;
  pk.s.h = h; pk.s.t = tag;
  __hip_atomic_store((unsigned long long*)p, pk.u,
                     __ATOMIC_RELAXED, __HIP_MEMORY_SCOPE_AGENT);
}

// ------------- embedding gather + layer0 input projection + hq tag zero ----
__global__ void emb_proj_k(const float* __restrict__ enc, const int* __restrict__ inp,
                           const float* __restrict__ Wih0, const float* __restrict__ bih0,
                           const float* __restrict__ bhh0, float* __restrict__ xw0,
                           float* __restrict__ hqz)
{
  __shared__ float xl[100];
  const int t = blockIdx.x;
  const int tid = threadIdx.x;
  // zero all {h,tag} pairs (agent-scope so scan's sc0sc1 polls see them)
  for (size_t i = (size_t)t*256 + tid; i < (size_t)NPAIRS_TOT; i += (size_t)TT*256)
    llc_store_pair(hqz + i*2, 0.f, 0u);
  if (tid < 100) {
    int q = t*100 + tid;
    int s = q / 1200;
    int rm = q - s*1200;
    int bb = rm / 300;
    int e  = rm - bb*300;
    int tok = inp[bb*25 + s];
    xl[tid] = enc[(long)tok*300 + e];
  }
  __syncthreads();
  for (int rr = 0; rr < 4; ++rr) {
    int row = rr*256 + tid;
    const float* wr = Wih0 + row*25;
    float bias = bih0[row] + bhh0[row];
    float a0 = bias, a1 = bias, a2 = bias, a3 = bias;
#pragma unroll
    for (int i = 0; i < 25; ++i) {
      float w = wr[i];
      a0 += w * xl[i];
      a1 += w * xl[25+i];
      a2 += w * xl[50+i];
      a3 += w * xl[75+i];
    }
    xw0[(t*4+0)*1024 + row] = a0;
    xw0[(t*4+1)*1024 + row] = a1;
    xw0[(t*4+2)*1024 + row] = a2;
    xw0[(t*4+3)*1024 + row] = a3;
  }
}

// ---------------- persistent 2-layer LSTM scan, fp16 MFMA, 6 WGs -----------
// WG 0..1 : layer0, units [wid*128, +128), 512 gate rows, K=256
// WG 2..5 : layer1, units [(wid-2)*64, +64), 256 gate rows, K=512=cat(y0,h1)
// Weights resident in VGPRs as SINGLE fp16 fragments (128 VGPR/thread ->
// provably resident at 512thr/WG, 2 waves/SIMD). Sync unchanged from R5:
// fused {h,tag} pairs via LLC, poll-all, 2 barriers/step, cell in register.
__global__ __launch_bounds__(512, 1) void scan_k(
    const float* __restrict__ Whh0, const float* __restrict__ Wih1,
    const float* __restrict__ Whh1, const float* __restrict__ bih1,
    const float* __restrict__ bhh1, const float* __restrict__ h0in,
    const float* __restrict__ c0in, const float* __restrict__ xw0,
    float* __restrict__ hq0, float* __restrict__ hq1,
    float* __restrict__ dout)
{
  const int wid  = blockIdx.x;
  const int tid  = threadIdx.x;
  const int lane = tid & 63;
  const int wv   = tid >> 6;          // wave 0..7
  const int ln15 = lane & 15;         // A-row in tile / D-col (batch)
  const int kg   = lane >> 4;         // k-group 0..3
  const int layer = (wid < 2) ? 0 : 1;

  // B-operand staging [b(16)][k + pad8]; stride 520 f16 = 1040B (16B-aligned)
  __shared__ _Float16 hb[16][520];
  __shared__ float    gl[512*5 + 4];  // gate pre-acts [local_row][b], pad 5

  // ---- weight fragments, single fp16. Linear k = kt*32 + kg*8 + j.
  f16x8 wf[32];
  if (layer == 0) {
#pragma unroll
    for (int q = 0; q < 4; ++q) {
      int r = (wv*4 + q)*16 + ln15;           // local row 0..511
      int g = r >> 7, ul = r & 127;
      const float* wr = Whh0 + (size_t)(g*256 + wid*128 + ul)*256;
#pragma unroll
      for (int kt = 0; kt < 8; ++kt) {
        f16x8 f;
#pragma unroll
        for (int jj = 0; jj < 8; ++jj) f[jj] = (_Float16)wr[kt*32 + kg*8 + jj];
        wf[q*8 + kt] = f;
      }
    }
  } else {
#pragma unroll
    for (int q = 0; q < 2; ++q) {
      int r = (wv*2 + q)*16 + ln15;           // local row 0..255
      int g = r >> 6, ul = r & 63;
      size_t grow = (size_t)(g*256 + (wid-2)*64 + ul);
      const float* wi = Wih1 + grow*256;
      const float* wh = Whh1 + grow*256;
#pragma unroll
      for (int kt = 0; kt < 16; ++kt) {
        const float* wr = (kt < 8) ? (wi + kt*32) : (wh + (kt-8)*32);
        f16x8 f;
#pragma unroll
        for (int jj = 0; jj < 8; ++jj) f[jj] = (_Float16)wr[kg*8 + jj];
        wf[q*16 + kt] = f;
      }
    }
  }

  // ---- gate-math thread state: (u,b) owns cell c[u][b] in a register
  //      L0: all 512 threads (128 units x 4b). L1: tid<256 (64 units x 4b).
  const int ul = tid >> 2, b = tid & 3;
  const bool gthr = (layer == 0) ? true : (tid < 256);
  int gu = 0; float cpr = 0.f, bs0=0.f, bs1=0.f, bs2=0.f, bs3=0.f;
  if (gthr) {
    gu = (layer == 0) ? (wid*128 + ul) : ((wid-2)*64 + ul);
    cpr = c0in[layer*1024 + b*256 + gu];
    if (layer == 1) {
      bs0 = bih1[0*256+gu] + bhh1[0*256+gu];
      bs1 = bih1[1*256+gu] + bhh1[1*256+gu];
      bs2 = bih1[2*256+gu] + bhh1[2*256+gu];
      bs3 = bih1[3*256+gu] + bhh1[3*256+gu];
    }
  }

  // zero B-operand batch cols 4..15 once (stay zero forever)
  for (int i = tid; i < 12*520; i += 512) hb[4 + i/520][i%520] = (_Float16)0.f;

  const int UN = layer ? 64 : 128;    // local units per gate

  for (int t = 0; t < TT; ++t) {
    // -- L0 gate-input prefetch (L2-cached; cheap)
    float xwa=0.f, xwb=0.f, xwc=0.f, xwd=0.f;
    if (layer == 0) {
      const float* xp = xw0 + (size_t)(t*4 + b)*1024 + gu;
      xwa = xp[0]; xwb = xp[256]; xwc = xp[512]; xwd = xp[768];
    }

    // -- poll fused {h,tag} pairs, stage to hb as fp16
    const int j  = tid >> 1;               // h-unit this thread stages
    const int b0 = (tid & 1) * 2;          // batches b0, b0+1
    if (layer == 0) {
      float2 v;
      if (t == 0) {
        v.x = h0in[(b0+0)*256 + j];
        v.y = h0in[(b0+1)*256 + j];
      } else {
        const float* pp = hq0 + ((size_t)(t-1)*1024 + (size_t)tid*2)*2;
        const unsigned tg = (unsigned)t;
        unsigned gd = 0; uint4 q;
        do { q = llc_load16(pp); }
        while ((q.y != tg || q.w != tg) && ++gd < (1u<<20));
        v.x = __uint_as_float(q.x); v.y = __uint_as_float(q.z);
      }
      hb[b0+0][j] = (_Float16)v.x;
      hb[b0+1][j] = (_Float16)v.y;
    } else {
      const float* py = hq0 + ((size_t)t*1024 + (size_t)tid*2)*2;   // y0[t]
      const unsigned tgy = (unsigned)(t+1);
      float2 vy, vh;
      if (t == 0) {
        unsigned gd = 0; uint4 q;
        do { q = llc_load16(py); }
        while ((q.y != tgy || q.w != tgy) && ++gd < (1u<<20));
        vy.x = __uint_as_float(q.x); vy.y = __uint_as_float(q.z);
        vh.x = h0in[1024 + (b0+0)*256 + j];
        vh.y = h0in[1024 + (b0+1)*256 + j];
      } else {
        const float* ph = hq1 + ((size_t)(t-1)*1024 + (size_t)tid*2)*2;
        const unsigned tgh = (unsigned)t;
        unsigned gd = 0; uint4 q1, q2;
        do { llc_load16x2(py, ph, q1, q2); }
        while ((q1.y != tgy || q1.w != tgy || q2.y != tgh || q2.w != tgh) &&
               ++gd < (1u<<20));
        vy.x = __uint_as_float(q1.x); vy.y = __uint_as_float(q1.z);
        vh.x = __uint_as_float(q2.x); vh.y = __uint_as_float(q2.z);
      }
      hb[b0+0][j]     = (_Float16)vy.x;
      hb[b0+1][j]     = (_Float16)vy.y;
      hb[b0+0][256+j] = (_Float16)vh.x;
      hb[b0+1][256+j] = (_Float16)vh.y;
    }
    __syncthreads();                    // B1: staging ready

    // -- MFMA: D[row][batch] over resident fp16 fragments
    if (layer == 0) {
      f32x4 acc[4];
#pragma unroll
      for (int q = 0; q < 4; ++q) acc[q] = (f32x4){0.f,0.f,0.f,0.f};
#pragma unroll
      for (int kt = 0; kt < 8; ++kt) {
        f16x8 bfr = *(const f16x8*)&hb[ln15][kt*32 + kg*8];
#pragma unroll
        for (int q = 0; q < 4; ++q)
          acc[q] = __builtin_amdgcn_mfma_f32_16x16x32_f16(wf[q*8+kt], bfr, acc[q], 0,0,0);
      }
      if (ln15 < 4) {
#pragma unroll
        for (int q = 0; q < 4; ++q)
#pragma unroll
          for (int i = 0; i < 4; ++i)
            gl[((wv*4+q)*16 + kg*4 + i)*5 + ln15] = acc[q][i];
      }
    } else {
      f32x4 acc[2];
#pragma unroll
      for (int q = 0; q < 2; ++q) acc[q] = (f32x4){0.f,0.f,0.f,0.f};
#pragma unroll
      for (int kt = 0; kt < 16; ++kt) {
        f16x8 bfr = *(const f16x8*)&hb[ln15][kt*32 + kg*8];
#pragma unroll
        for (int q = 0; q < 2; ++q)
          acc[q] = __builtin_amdgcn_mfma_f32_16x16x32_f16(wf[q*16+kt], bfr, acc[q], 0,0,0);
      }
      if (ln15 < 4) {
#pragma unroll
        for (int q = 0; q < 2; ++q)
#pragma unroll
          for (int i = 0; i < 4; ++i)
            gl[((wv*2+q)*16 + kg*4 + i)*5 + ln15] = acc[q][i];
      }
    }
    __syncthreads();                    // B2: gates ready

    // -- gate math: thread (ul,b), cell in register, publish {h,tag}
    if (gthr) {
      float gi = gl[(0*UN + ul)*5 + b] + (layer ? bs0 : xwa);
      float gf = gl[(1*UN + ul)*5 + b] + (layer ? bs1 : xwb);
      float gc = gl[(2*UN + ul)*5 + b] + (layer ? bs2 : xwc);
      float go = gl[(3*UN + ul)*5 + b] + (layer ? bs3 : xwd);
      float cn = sigf(gf)*cpr + sigf(gi)*tahf(gc);
      float hn = sigf(go)*tahf(cn);
      cpr = cn;
      float* hq = layer ? hq1 : hq0;
      llc_store_pair(hq + ((size_t)t*1024 + gu*4 + b)*2, hn, (unsigned)(t+1));
      if (t == TT-1) {
        dout[400000 + layer*1024 + b*256 + gu] = hn;
        dout[400000 + 2048 + layer*1024 + b*256 + gu] = cn;
      }
    }
    // no 3rd barrier: hb WAR is ordered by B2(t) -> stage(t+1);
    // gl WAR is ordered by gate-read(t) -> B1(t+1) -> MFMA-write(t+1).
  }
}

// ---------------- fc + relu + vocab decode --------------------------------
__global__ void decode_k(const float* __restrict__ y1p, const float* __restrict__ fcW,
                         const float* __restrict__ fcb, const float* __restrict__ decW,
                         const float* __restrict__ decb, float* __restrict__ dout)
{
  __shared__ float y1[1024];   // [j][b]
  __shared__ float o10[40];    // [kk][b]
  const int tid = threadIdx.x;
#pragma unroll
  for (int b = 0; b < 4; ++b)
    y1[tid*4 + b] = y1p[(size_t)(tid*4 + b)*2];   // strip tags
  __syncthreads();
  if (tid < 40) {
    int kk = tid >> 2, b = tid & 3;
    float a = fcb[kk];
    for (int j = 0; j < 256; ++j) a += fcW[kk*256 + j] * y1[j*4 + b];
    o10[kk*4 + b] = fmaxf(a, 0.f);
  }
  __syncthreads();
  int v = blockIdx.x*256 + tid;
  if (v < 100000) {
    const float* dr = decW + (size_t)v*10;
    float bias = decb[v];
    float a0 = bias, a1 = bias, a2 = bias, a3 = bias;
#pragma unroll
    for (int kk = 0; kk < 10; ++kk) {
      float w = dr[kk];
      a0 += w * o10[kk*4+0];
      a1 += w * o10[kk*4+1];
      a2 += w * o10[kk*4+2];
      a3 += w * o10[kk*4+3];
    }
    float4 o; o.x = a0; o.y = a1; o.z = a2; o.w = a3;
    ((float4*)dout)[v] = o;   // decoded.T[v][0..3]
  }
}

extern "C" void kernel_launch(void* const* d_in, const int* in_sizes, int n_in,
                              void* d_out, int out_size, void* d_ws, size_t ws_size,
                              hipStream_t stream)
{
  const float* enc  = (const float*)d_in[0];
  const float* h0in = (const float*)d_in[1];
  const float* c0in = (const float*)d_in[2];
  const float* Wih0 = (const float*)d_in[3];
  const float* Whh0 = (const float*)d_in[4];
  const float* bih0 = (const float*)d_in[5];
  const float* bhh0 = (const float*)d_in[6];
  const float* Wih1 = (const float*)d_in[7];
  const float* Whh1 = (const float*)d_in[8];
  const float* bih1 = (const float*)d_in[9];
  const float* bhh1 = (const float*)d_in[10];
  const float* fcW  = (const float*)d_in[11];
  const float* fcb  = (const float*)d_in[12];
  const float* decW = (const float*)d_in[13];
  const float* decb = (const float*)d_in[14];
  const int*   inp  = (const int*)d_in[15];

  float* ws   = (float*)d_ws;
  float* xw0  = ws + XW0_OFF;
  float* hq0  = ws + HQ0_OFF;
  float* hq1  = ws + HQ1_OFF;
  float* dout = (float*)d_out;

  emb_proj_k<<<TT, 256, 0, stream>>>(enc, inp, Wih0, bih0, bhh0, xw0, hq0);
  scan_k<<<6, 512, 0, stream>>>(Whh0, Wih1, Whh1, bih1, bhh1,
                                h0in, c0in, xw0, hq0, hq1, dout);
  decode_k<<<(100000 + 255)/256, 256, 0, stream>>>(hq1 + (size_t)(TT-1)*1024*2,
                                                   fcW, fcb, decW, decb, dout);
}